// Round 5
// baseline (380.299 us; speedup 1.0000x reference)
//
#include <hip/hip_runtime.h>

// LSTM: B=4096, T=512, INPUT=1, HIDDEN=32, OUTPUT=1 (fp32)
// One 64-lane wave per block, 2 batch elements (one per 32-lane half).
// Lane j owns hidden unit j: 4 recurrent weight rows (128 fp32) in VGPRs.
//
// KEY FIX vs rounds 1-4: the h exchange is done with ds_bpermute on the
// REGISTER value of h — pure SSA dataflow, no LDS buffer, no memory fence.
// Rounds 1-4 all had a per-step memory fence/clobber (for the LDS h row),
// which legally forces the W_hh loads to re-execute every timestep (the asm
// clobber may write through W_hh), so weights were never register-resident
// (VGPR_Count stuck at 84, scratch warm-up dispatches). With a fence-free
// loop the weight loads are loop-invariant, hoisted, and stay in VGPRs.
//
// log2(e) folded into W/b at load: every activation is rcp(1+exp2(-a)).

#define HID 32
#define TSTEPS 512
#define BPW 2            // batch elements per wave/block
#define BLOCK 64
#define L2E 1.44269504088896340736f

__device__ __forceinline__ float rcp_fast(float x) {
    return __builtin_amdgcn_rcpf(x);            // v_rcp_f32
}
__device__ __forceinline__ float exp2_fast(float x) {
    return __builtin_amdgcn_exp2f(x);           // v_exp_f32
}
// a pre-scaled by log2(e): sigmoid(a/L2E)
__device__ __forceinline__ float sigmoid_l2(float a) {
    return rcp_fast(1.0f + exp2_fast(-a));
}
// a pre-scaled by 2*log2(e): tanh(a/(2*L2E))
__device__ __forceinline__ float tanh_l2(float a) {
    return fmaf(2.0f, rcp_fast(1.0f + exp2_fast(-a)), -1.0f);
}

__global__ __launch_bounds__(BLOCK, 2)
void lstm_fused_kernel(const float* __restrict__ x,
                       const float* __restrict__ W_ih,
                       const float* __restrict__ W_hh,
                       const float* __restrict__ b_ih,
                       const float* __restrict__ b_hh,
                       const float* __restrict__ W_fc,
                       const float* __restrict__ b_fc,
                       float* __restrict__ out)
{
    __shared__ __align__(16) float x_s[BPW * TSTEPS];   // 4 KiB, read-only in loop

    const int tid = threadIdx.x;
    const int lb  = tid >> 5;        // local batch 0..1 (half-wave)
    const int j   = tid & 31;        // hidden unit
    const int b0  = blockIdx.x * BPW;

    // ---- stage x (coalesced float4); same wave consumes it: same-wave DS
    // ops are in-order and the compiler tracks the LDS RAW dependency, so
    // no barrier is needed (block = 1 wave). ----
    {
        const float4* xsrc = reinterpret_cast<const float4*>(x + (size_t)b0 * TSTEPS);
        float4* xdst = reinterpret_cast<float4*>(x_s);
        #pragma unroll
        for (int k = 0; k < (BPW * TSTEPS) / (4 * BLOCK); ++k)
            xdst[tid + k * BLOCK] = xsrc[tid + k * BLOCK];
    }

    // ---- per-unit weights into registers, pre-scaled (loop-invariant,
    // fence-free loop => these hoist and stay resident) ----
    // gate 0=i, 1=f, 2=g, 3=o ; scale L2E for i/f/o, 2*L2E for g
    float w0[HID], w1[HID], w2[HID], w3[HID];
    {
        const float4* r0 = reinterpret_cast<const float4*>(W_hh + (size_t)(0 * HID + j) * HID);
        const float4* r1 = reinterpret_cast<const float4*>(W_hh + (size_t)(1 * HID + j) * HID);
        const float4* r2 = reinterpret_cast<const float4*>(W_hh + (size_t)(2 * HID + j) * HID);
        const float4* r3 = reinterpret_cast<const float4*>(W_hh + (size_t)(3 * HID + j) * HID);
        #pragma unroll
        for (int k = 0; k < HID / 4; ++k) {
            float4 v;
            v = r0[k]; w0[4*k]=v.x*L2E;      w0[4*k+1]=v.y*L2E;      w0[4*k+2]=v.z*L2E;      w0[4*k+3]=v.w*L2E;
            v = r1[k]; w1[4*k]=v.x*L2E;      w1[4*k+1]=v.y*L2E;      w1[4*k+2]=v.z*L2E;      w1[4*k+3]=v.w*L2E;
            v = r2[k]; w2[4*k]=v.x*2.0f*L2E; w2[4*k+1]=v.y*2.0f*L2E; w2[4*k+2]=v.z*2.0f*L2E; w2[4*k+3]=v.w*2.0f*L2E;
            v = r3[k]; w3[4*k]=v.x*L2E;      w3[4*k+1]=v.y*L2E;      w3[4*k+2]=v.z*L2E;      w3[4*k+3]=v.w*L2E;
        }
    }
    const float wih0 = W_ih[j]         * L2E;
    const float wih1 = W_ih[HID + j]   * L2E;
    const float wih2 = W_ih[2*HID + j] * 2.0f * L2E;
    const float wih3 = W_ih[3*HID + j] * L2E;
    const float bs0  = (b_ih[j]         + b_hh[j])         * L2E;
    const float bs1  = (b_ih[HID + j]   + b_hh[HID + j])   * L2E;
    const float bs2  = (b_ih[2*HID + j] + b_hh[2*HID + j]) * 2.0f * L2E;
    const float bs3  = (b_ih[3*HID + j] + b_hh[3*HID + j]) * L2E;

    // byte base for ds_bpermute: lanes 0-31 pull lanes 0..31 (batch 0),
    // lanes 32-63 pull lanes 32..63 (batch 1)
    const int bp_base = (tid & 32) << 2;

    float c = 0.0f, hcur = 0.0f;

    // ---- recurrence: ZERO fences/barriers — h moves lane-to-lane as pure
    // register dataflow via ds_bpermute (src operand = previous iteration's
    // hcur SSA value => ordering is enforced by data dependence alone) ----
    #pragma unroll 1
    for (int t = 0; t < TSTEPS; ++t) {
        const float xv  = x_s[lb * TSTEPS + t];
        const int   h_i = __float_as_int(hcur);

        float a0 = fmaf(xv, wih0, bs0);
        float a1 = fmaf(xv, wih1, bs1);
        float a2 = fmaf(xv, wih2, bs2);
        float a3 = fmaf(xv, wih3, bs3);

        #pragma unroll
        for (int m = 0; m < HID; m += 4) {
            const float h0 = __int_as_float(__builtin_amdgcn_ds_bpermute(bp_base + 4*(m+0), h_i));
            const float h1 = __int_as_float(__builtin_amdgcn_ds_bpermute(bp_base + 4*(m+1), h_i));
            const float h2 = __int_as_float(__builtin_amdgcn_ds_bpermute(bp_base + 4*(m+2), h_i));
            const float h3 = __int_as_float(__builtin_amdgcn_ds_bpermute(bp_base + 4*(m+3), h_i));
            a0 = fmaf(h0, w0[m  ], a0);
            a1 = fmaf(h0, w1[m  ], a1);
            a2 = fmaf(h0, w2[m  ], a2);
            a3 = fmaf(h0, w3[m  ], a3);
            a0 = fmaf(h1, w0[m+1], a0);
            a1 = fmaf(h1, w1[m+1], a1);
            a2 = fmaf(h1, w2[m+1], a2);
            a3 = fmaf(h1, w3[m+1], a3);
            a0 = fmaf(h2, w0[m+2], a0);
            a1 = fmaf(h2, w1[m+2], a1);
            a2 = fmaf(h2, w2[m+2], a2);
            a3 = fmaf(h2, w3[m+2], a3);
            a0 = fmaf(h3, w0[m+3], a0);
            a1 = fmaf(h3, w1[m+3], a1);
            a2 = fmaf(h3, w2[m+3], a2);
            a3 = fmaf(h3, w3[m+3], a3);
        }

        const float ig = sigmoid_l2(a0);
        const float fg = sigmoid_l2(a1);
        const float gg = tanh_l2(a2);
        const float og = sigmoid_l2(a3);
        c    = fmaf(fg, c, ig * gg);
        hcur = og * tanh_l2((2.0f * L2E) * c);
    }

    // ---- final FC: out[b] = dot(h_T, W_fc) + b_fc ----
    float p = hcur * W_fc[j];
    #pragma unroll
    for (int off = 16; off >= 1; off >>= 1)
        p += __shfl_xor(p, off);   // xor masks <=16 stay within each half
    if (j == 0)
        out[b0 + lb] = p + b_fc[0];
}

extern "C" void kernel_launch(void* const* d_in, const int* in_sizes, int n_in,
                              void* d_out, int out_size, void* d_ws, size_t ws_size,
                              hipStream_t stream) {
    const float* x    = (const float*)d_in[0];
    const float* W_ih = (const float*)d_in[1];
    const float* W_hh = (const float*)d_in[2];
    const float* b_ih = (const float*)d_in[3];
    const float* b_hh = (const float*)d_in[4];
    const float* W_fc = (const float*)d_in[5];
    const float* b_fc = (const float*)d_in[6];
    float* out = (float*)d_out;

    const int B = in_sizes[0] / TSTEPS;   // 4096 (INPUT=1)
    const int grid = B / BPW;             // 2048 blocks, 1 wave each
    lstm_fused_kernel<<<grid, BLOCK, 0, stream>>>(x, W_ih, W_hh, b_ih, b_hh,
                                                  W_fc, b_fc, out);
}

// Round 6
// 281.428 us; speedup vs baseline: 1.3513x; 1.3513x over previous
//
#include <hip/hip_runtime.h>

// LSTM: B=4096, T=512, INPUT=1, HIDDEN=32, OUTPUT=1 (fp32)
// One 64-lane wave per block, 2 batch elements (one per 32-lane half).
// Lane j owns hidden unit j: 4 recurrent weight rows (128 fp32) in VGPRs.
//
// Round-6 synthesis of two independently-diagnosed bugs:
//  (a) ANY per-step memory fence/clobber is a potential store through W_hh
//      => weight loads can't be hoisted => reloaded every timestep.
//      Fix: NO fences at all. The LDS h exchange is ordered by the
//      may-alias dependence (store h_s[lb][j] -> next-iter reads h_s[lb][*])
//      which the compiler must preserve, plus same-wave DS ops execute
//      in-order in HW. Block = 1 wave, so no barrier is needed either.
//      (Validated by round 5: barrier-free same-wave LDS staging, absmax 0.)
//  (b) __launch_bounds__(64,2) sets only MIN waves/EU; the scheduler still
//      targets max occupancy [2..8] and demotes the 128 weights to shrink
//      register pressure (VGPR stuck at 84-104 across rounds 1-5).
//      Fix: amdgpu_waves_per_eu(2,2) pins min=max=2 (the grid only supplies
//      2 waves/SIMD anyway) => RA budget 256 VGPR => weights stay resident.
//
// log2(e) folded into W/b at load: every activation is rcp(1+exp2(-a)).

#define HID 32
#define TSTEPS 512
#define BPW 2            // batch elements per wave/block
#define BLOCK 64
#define L2E 1.44269504088896340736f

__device__ __forceinline__ float rcp_fast(float x) {
    return __builtin_amdgcn_rcpf(x);            // v_rcp_f32
}
__device__ __forceinline__ float exp2_fast(float x) {
    return __builtin_amdgcn_exp2f(x);           // v_exp_f32
}
// a pre-scaled by log2(e): sigmoid(a/L2E)
__device__ __forceinline__ float sigmoid_l2(float a) {
    return rcp_fast(1.0f + exp2_fast(-a));
}
// a pre-scaled by 2*log2(e): tanh(a/(2*L2E))
__device__ __forceinline__ float tanh_l2(float a) {
    return fmaf(2.0f, rcp_fast(1.0f + exp2_fast(-a)), -1.0f);
}

__global__ __launch_bounds__(BLOCK)
__attribute__((amdgpu_waves_per_eu(2, 2)))
void lstm_fused_kernel(const float* __restrict__ x,
                       const float* __restrict__ W_ih,
                       const float* __restrict__ W_hh,
                       const float* __restrict__ b_ih,
                       const float* __restrict__ b_hh,
                       const float* __restrict__ W_fc,
                       const float* __restrict__ b_fc,
                       float* __restrict__ out)
{
    __shared__ __align__(16) float x_s[BPW * TSTEPS];   // 4 KiB
    __shared__ __align__(16) float h_s[BPW][HID];       // 256 B

    const int tid = threadIdx.x;
    const int lb  = tid >> 5;        // local batch 0..1 (half-wave)
    const int j   = tid & 31;        // hidden unit
    const int b0  = blockIdx.x * BPW;

    // ---- stage x (coalesced float4). Same wave produces and consumes:
    // same-wave DS ops are in-order, no barrier needed (block = 1 wave). ----
    {
        const float4* xsrc = reinterpret_cast<const float4*>(x + (size_t)b0 * TSTEPS);
        float4* xdst = reinterpret_cast<float4*>(x_s);
        #pragma unroll
        for (int k = 0; k < (BPW * TSTEPS) / (4 * BLOCK); ++k)
            xdst[tid + k * BLOCK] = xsrc[tid + k * BLOCK];
    }

    // ---- per-unit weights into registers, pre-scaled (loop-invariant;
    // with a fence-free loop these hoist and stay resident) ----
    // gate 0=i, 1=f, 2=g, 3=o ; scale L2E for i/f/o, 2*L2E for g
    float w0[HID], w1[HID], w2[HID], w3[HID];
    {
        const float4* r0 = reinterpret_cast<const float4*>(W_hh + (size_t)(0 * HID + j) * HID);
        const float4* r1 = reinterpret_cast<const float4*>(W_hh + (size_t)(1 * HID + j) * HID);
        const float4* r2 = reinterpret_cast<const float4*>(W_hh + (size_t)(2 * HID + j) * HID);
        const float4* r3 = reinterpret_cast<const float4*>(W_hh + (size_t)(3 * HID + j) * HID);
        #pragma unroll
        for (int k = 0; k < HID / 4; ++k) {
            float4 v;
            v = r0[k]; w0[4*k]=v.x*L2E;      w0[4*k+1]=v.y*L2E;      w0[4*k+2]=v.z*L2E;      w0[4*k+3]=v.w*L2E;
            v = r1[k]; w1[4*k]=v.x*L2E;      w1[4*k+1]=v.y*L2E;      w1[4*k+2]=v.z*L2E;      w1[4*k+3]=v.w*L2E;
            v = r2[k]; w2[4*k]=v.x*2.0f*L2E; w2[4*k+1]=v.y*2.0f*L2E; w2[4*k+2]=v.z*2.0f*L2E; w2[4*k+3]=v.w*2.0f*L2E;
            v = r3[k]; w3[4*k]=v.x*L2E;      w3[4*k+1]=v.y*L2E;      w3[4*k+2]=v.z*L2E;      w3[4*k+3]=v.w*L2E;
        }
    }
    const float wih0 = W_ih[j]         * L2E;
    const float wih1 = W_ih[HID + j]   * L2E;
    const float wih2 = W_ih[2*HID + j] * 2.0f * L2E;
    const float wih3 = W_ih[3*HID + j] * L2E;
    const float bs0  = (b_ih[j]         + b_hh[j])         * L2E;
    const float bs1  = (b_ih[HID + j]   + b_hh[HID + j])   * L2E;
    const float bs2  = (b_ih[2*HID + j] + b_hh[2*HID + j]) * 2.0f * L2E;
    const float bs3  = (b_ih[3*HID + j] + b_hh[3*HID + j]) * L2E;

    // ---- init state (same-wave in-order DS: no fence needed) ----
    h_s[lb][j] = 0.0f;
    float c = 0.0f, hcur = 0.0f;

    // ---- recurrence: ZERO fences/barriers. Ordering comes from the
    // may-alias dependence store(h_s) -> next-iter loads(h_s), which the
    // compiler cannot reorder, and in-order same-wave DS execution. ----
    #pragma unroll 1
    for (int t = 0; t < TSTEPS; ++t) {
        const float xv = x_s[lb * TSTEPS + t];

        float a0 = fmaf(xv, wih0, bs0);
        float a1 = fmaf(xv, wih1, bs1);
        float a2 = fmaf(xv, wih2, bs2);
        float a3 = fmaf(xv, wih3, bs3);

        const float4* hr = reinterpret_cast<const float4*>(&h_s[lb][0]);
        #pragma unroll
        for (int k = 0; k < HID / 4; ++k) {
            float4 hv = hr[k];
            a0 = fmaf(hv.x, w0[4*k  ], a0);
            a1 = fmaf(hv.x, w1[4*k  ], a1);
            a2 = fmaf(hv.x, w2[4*k  ], a2);
            a3 = fmaf(hv.x, w3[4*k  ], a3);
            a0 = fmaf(hv.y, w0[4*k+1], a0);
            a1 = fmaf(hv.y, w1[4*k+1], a1);
            a2 = fmaf(hv.y, w2[4*k+1], a2);
            a3 = fmaf(hv.y, w3[4*k+1], a3);
            a0 = fmaf(hv.z, w0[4*k+2], a0);
            a1 = fmaf(hv.z, w1[4*k+2], a1);
            a2 = fmaf(hv.z, w2[4*k+2], a2);
            a3 = fmaf(hv.z, w3[4*k+2], a3);
            a0 = fmaf(hv.w, w0[4*k+3], a0);
            a1 = fmaf(hv.w, w1[4*k+3], a1);
            a2 = fmaf(hv.w, w2[4*k+3], a2);
            a3 = fmaf(hv.w, w3[4*k+3], a3);
        }

        const float ig = sigmoid_l2(a0);
        const float fg = sigmoid_l2(a1);
        const float gg = tanh_l2(a2);
        const float og = sigmoid_l2(a3);
        c    = fmaf(fg, c, ig * gg);
        hcur = og * tanh_l2((2.0f * L2E) * c);

        h_s[lb][j] = hcur;
    }

    // ---- final FC: out[b] = dot(h_T, W_fc) + b_fc ----
    float p = hcur * W_fc[j];
    #pragma unroll
    for (int off = 16; off >= 1; off >>= 1)
        p += __shfl_xor(p, off);   // xor masks <=16 stay within each half
    if (j == 0)
        out[b0 + lb] = p + b_fc[0];
}

extern "C" void kernel_launch(void* const* d_in, const int* in_sizes, int n_in,
                              void* d_out, int out_size, void* d_ws, size_t ws_size,
                              hipStream_t stream) {
    const float* x    = (const float*)d_in[0];
    const float* W_ih = (const float*)d_in[1];
    const float* W_hh = (const float*)d_in[2];
    const float* b_ih = (const float*)d_in[3];
    const float* b_hh = (const float*)d_in[4];
    const float* W_fc = (const float*)d_in[5];
    const float* b_fc = (const float*)d_in[6];
    float* out = (float*)d_out;

    const int B = in_sizes[0] / TSTEPS;   // 4096 (INPUT=1)
    const int grid = B / BPW;             // 2048 blocks, 1 wave each
    lstm_fused_kernel<<<grid, BLOCK, 0, stream>>>(x, W_ih, W_hh, b_ih, b_hh,
                                                  W_fc, b_fc, out);
}